// Round 5
// baseline (936.111 us; speedup 1.0000x reference)
//
#include <hip/hip_runtime.h>

static constexpr int NN = 100000;   // nodes
static constexpr int NE = 3200000;  // edges
static constexpr float EPS = 1e-5f;
static constexpr int SCAN_B = 256;
static constexpr int NBLK = (NN + SCAN_B - 1) / SCAN_B;   // 391
static constexpr int BSH  = 5;                            // bucket shift
static constexpr int NBUK = NN >> BSH;                    // 3125 (exact: 3125*32=100000)
static constexpr int NGRP = 8;                            // XCD groups
static constexpr int BPG  = (NBUK + NGRP - 1) / NGRP;     // 391 buckets per group
static constexpr int NPG  = BPG << BSH;                   // 12512 nodes per group
static constexpr int CH   = 16384;                        // edge chunk per block
static constexpr int NCHUNK = (NE + CH - 1) / CH;         // 196

// ---- histogram of dst ----------------------------------------------------
__global__ void k_hist(const int* __restrict__ dst, int* __restrict__ cnt) {
    int e = blockIdx.x * blockDim.x + threadIdx.x;
    if (e < NE) atomicAdd(&cnt[dst[e]], 1);
}

__global__ void k_dinv(const int* __restrict__ cnt, float* __restrict__ dinv) {
    int i = blockIdx.x * blockDim.x + threadIdx.x;
    if (i < NN) dinv[i] = rsqrtf((float)cnt[i] + 1.0f);
}

// ---- exclusive scan over cnt -> rowp -------------------------------------
__global__ void k_scan1(const int* __restrict__ cnt, int* __restrict__ excl,
                        int* __restrict__ bsum) {
    __shared__ int s[SCAN_B];
    int gid = blockIdx.x * SCAN_B + threadIdx.x;
    int v = (gid < NN) ? cnt[gid] : 0;
    s[threadIdx.x] = v;
    __syncthreads();
    for (int off = 1; off < SCAN_B; off <<= 1) {
        int t = (threadIdx.x >= off) ? s[threadIdx.x - off] : 0;
        __syncthreads();
        s[threadIdx.x] += t;
        __syncthreads();
    }
    if (gid < NN) excl[gid] = s[threadIdx.x] - v;
    if (threadIdx.x == SCAN_B - 1) bsum[blockIdx.x] = s[threadIdx.x];
}

__global__ void k_scan2(int* __restrict__ bsum) {
    __shared__ int s[512];
    int tid = threadIdx.x;
    int v = (tid < NBLK) ? bsum[tid] : 0;
    s[tid] = v;
    __syncthreads();
    for (int off = 1; off < 512; off <<= 1) {
        int t = (tid >= off) ? s[tid - off] : 0;
        __syncthreads();
        s[tid] += t;
        __syncthreads();
    }
    if (tid < NBLK) bsum[tid] = s[tid] - v;
}

__global__ void k_scan3(int* __restrict__ excl, const int* __restrict__ bsum) {
    int i = blockIdx.x * blockDim.x + threadIdx.x;
    if (i < NN) excl[i] += bsum[i / SCAN_B];
}

// ---- seed coarse bucket cursors: bcur[b] = rowp[b<<BSH] ------------------
__global__ void k_bseed(const int* __restrict__ rowp, int* __restrict__ bcur) {
    int b = blockIdx.x * blockDim.x + threadIdx.x;
    if (b < NBUK) bcur[b] = rowp[b << BSH];
}

// ---- pass A: XCD-owned bucket partition ----------------------------------
// group g = blockIdx&7 owns node range [g*NPG, (g+1)*NPG); with round-robin
// block->XCD dispatch, all writers of a bucket's ebuf region are on one XCD,
// so its L2 assembles full 64B lines before writeback.
__global__ void k_bucket(const int* __restrict__ src, const int* __restrict__ dst,
                         int* __restrict__ bcur, unsigned* __restrict__ ebuf) {
    int g = blockIdx.x & 7;
    int c = blockIdx.x >> 3;
    int lo = c * CH;
    int hi = min(lo + CH, NE);
    int nlo = g * NPG, nhi = nlo + NPG;
    for (int e = lo + threadIdx.x; e < hi; e += blockDim.x) {
        int d = dst[e];
        if (d >= nlo && d < nhi) {
            int pos = atomicAdd(&bcur[d >> BSH], 1);
            ebuf[pos] = ((unsigned)(d & ((1 << BSH) - 1)) << 17) | (unsigned)src[e];
        }
    }
}

// ---- pass B: fine fill within bucket (LDS cursors, L2-local stripe) ------
__global__ void k_fill2(const unsigned* __restrict__ ebuf, const int* __restrict__ rowp,
                        int* __restrict__ csr) {
    __shared__ int lcur[1 << BSH];
    int b = blockIdx.x;
    int base = b << BSH;
    if (threadIdx.x < (1 << BSH)) lcur[threadIdx.x] = rowp[base + threadIdx.x];
    __syncthreads();
    int lo  = rowp[base];
    int end = (b == NBUK - 1) ? NE : rowp[base + (1 << BSH)];
    for (int i = lo + threadIdx.x; i < end; i += blockDim.x) {
        unsigned p = ebuf[i];
        int dl = (int)(p >> 17);
        int pos = atomicAdd(&lcur[dl], 1);
        csr[pos] = (int)(p & 0x1FFFFu);
    }
}

// ---- layer-1 staging: q[i, 0..7] = dinv[i]*x[i, 0..4], pad 0 -------------
__global__ void k_stage1(const float* __restrict__ x, const float* __restrict__ dinv,
                         float* __restrict__ q) {
    int idx = blockIdx.x * blockDim.x + threadIdx.x;
    if (idx >= NN * 8) return;
    int i = idx >> 3, k = idx & 7;
    q[idx] = (k < 5) ? x[i * 5 + k] * dinv[i] : 0.f;
}

// ---- hs = dinv[i] * (in[i,:] @ W), OUTP-padded rows ----------------------
template<int IN, int OUT, int OUTP>
__global__ void k_linear_scale(const float* __restrict__ in, const float* __restrict__ W,
                               const float* __restrict__ dinv, float* __restrict__ hs) {
    int idx = blockIdx.x * blockDim.x + threadIdx.x;
    if (idx >= NN * OUTP) return;
    int i = idx / OUTP, f = idx - i * OUTP;
    float a = 0.f;
    if (f < OUT) {
        #pragma unroll
        for (int k = 0; k < IN; ++k) a += in[i * IN + k] * W[k * OUT + f];
        a *= dinv[i];
    }
    hs[idx] = a;
}

// ---- wave-per-node float4 gather + fused finalize -------------------------
// F = padded feature width (multiple of 4). MODE: 0 scale only (write F),
// 1 bias+relu, 2 bias+bn+relu, 3 bias only + write 3 floats (logits).
template<int F, int MODE>
__global__ void k_gather(const int* __restrict__ row_ptr, const int* __restrict__ cnt,
                         const int* __restrict__ csr, const float* __restrict__ hs,
                         const float* __restrict__ dinv, const float* __restrict__ b,
                         const float* __restrict__ g, const float* __restrict__ be,
                         const float* __restrict__ m, const float* __restrict__ vv,
                         float* __restrict__ out) {
    constexpr int F4  = F / 4;        // lanes per edge
    constexpr int EPI = 64 / F4;      // edges per iteration

    int node = (blockIdx.x * blockDim.x + threadIdx.x) >> 6;
    if (node >= NN) return;
    int lane = threadIdx.x & 63;
    int c = lane & (F4 - 1);          // float4 column within row
    int e = lane / F4;                // edge slot

    int start = row_ptr[node];
    int n     = cnt[node];

    float4 a  = make_float4(0.f, 0.f, 0.f, 0.f);
    float4 a2 = make_float4(0.f, 0.f, 0.f, 0.f);
    for (int j = e; j < n; j += 2 * EPI) {
        int s = csr[start + j];
        float4 v = reinterpret_cast<const float4*>(hs + (size_t)s * F)[c];
        int j2 = j + EPI;
        if (j2 < n) {
            int s2 = csr[start + j2];
            float4 v2 = reinterpret_cast<const float4*>(hs + (size_t)s2 * F)[c];
            a2.x += v2.x; a2.y += v2.y; a2.z += v2.z; a2.w += v2.w;
        }
        a.x += v.x; a.y += v.y; a.z += v.z; a.w += v.w;
    }
    a.x += a2.x; a.y += a2.y; a.z += a2.z; a.w += a2.w;
    #pragma unroll
    for (int mask = F4; mask < 64; mask <<= 1) {
        a.x += __shfl_xor(a.x, mask);
        a.y += __shfl_xor(a.y, mask);
        a.z += __shfl_xor(a.z, mask);
        a.w += __shfl_xor(a.w, mask);
    }

    if (lane < F4) {
        float4 self = reinterpret_cast<const float4*>(hs + (size_t)node * F)[lane];
        float di = dinv[node];
        float4 z;
        z.x = di * (a.x + self.x);
        z.y = di * (a.y + self.y);
        z.z = di * (a.z + self.z);
        z.w = di * (a.w + self.w);
        if constexpr (MODE >= 1) {
            int f0 = lane * 4;
            z.x += b[f0 + 0]; z.y += b[f0 + 1];
            z.z += b[f0 + 2]; z.w += (MODE == 3 ? 0.f : b[f0 + 3]);
            if constexpr (MODE == 2) {
                z.x = (z.x - m[f0+0]) * rsqrtf(vv[f0+0] + EPS) * g[f0+0] + be[f0+0];
                z.y = (z.y - m[f0+1]) * rsqrtf(vv[f0+1] + EPS) * g[f0+1] + be[f0+1];
                z.z = (z.z - m[f0+2]) * rsqrtf(vv[f0+2] + EPS) * g[f0+2] + be[f0+2];
                z.w = (z.w - m[f0+3]) * rsqrtf(vv[f0+3] + EPS) * g[f0+3] + be[f0+3];
            }
            if constexpr (MODE == 1 || MODE == 2) {
                z.x = fmaxf(z.x, 0.f); z.y = fmaxf(z.y, 0.f);
                z.z = fmaxf(z.z, 0.f); z.w = fmaxf(z.w, 0.f);
            }
        }
        if constexpr (MODE == 3) {
            float* o = out + (size_t)node * 3;
            o[0] = z.x; o[1] = z.y; o[2] = z.z;
        } else {
            reinterpret_cast<float4*>(out + (size_t)node * F)[lane] = z;
        }
    }
}

// ---- layer-1 tail: X1 = relu(bn(G[:, :5] @ W1 + b1)) ----------------------
__global__ void k_lin1(const float* __restrict__ G, const float* __restrict__ W1,
                       const float* __restrict__ b1, const float* __restrict__ g1,
                       const float* __restrict__ be1, const float* __restrict__ m1,
                       const float* __restrict__ v1, float* __restrict__ X) {
    int idx = blockIdx.x * blockDim.x + threadIdx.x;
    if (idx >= NN * 64) return;
    int i = idx >> 6, f = idx & 63;
    const float* gr = G + (size_t)i * 8;
    float z = b1[f];
    #pragma unroll
    for (int k = 0; k < 5; ++k) z += gr[k] * W1[k * 64 + f];
    z = (z - m1[f]) * rsqrtf(v1[f] + EPS) * g1[f] + be1[f];
    X[idx] = fmaxf(z, 0.f);
}

extern "C" void kernel_launch(void* const* d_in, const int* in_sizes, int n_in,
                              void* d_out, int out_size, void* d_ws, size_t ws_size,
                              hipStream_t stream) {
    const float* x   = (const float*)d_in[0];
    const int*   src = (const int*)  d_in[1];
    const int*   dst = (const int*)  d_in[2];
    const float* W1  = (const float*)d_in[3];
    const float* b1  = (const float*)d_in[4];
    const float* g1  = (const float*)d_in[5];
    const float* be1 = (const float*)d_in[6];
    const float* m1  = (const float*)d_in[7];
    const float* v1  = (const float*)d_in[8];
    const float* W2  = (const float*)d_in[9];
    const float* b2  = (const float*)d_in[10];
    const float* g2  = (const float*)d_in[11];
    const float* be2 = (const float*)d_in[12];
    const float* m2  = (const float*)d_in[13];
    const float* v2  = (const float*)d_in[14];
    const float* W3  = (const float*)d_in[15];
    const float* b3  = (const float*)d_in[16];
    const float* W4  = (const float*)d_in[17];
    const float* b4  = (const float*)d_in[18];
    float* out = (float*)d_out;

    // workspace layout (4-byte units)
    char* wsb = (char*)d_ws;
    float*    dinv   = (float*)wsb;                    // 100352
    int*      cnt    = (int*)(wsb + 100352ull * 4);
    int*      rowp   = (int*)(wsb + 200704ull * 4);
    int*      bsum   = (int*)(wsb + 301056ull * 4);    // 512
    int*      bcur   = (int*)(wsb + 301568ull * 4);    // 3584 pad
    int*      csr    = (int*)(wsb + 305152ull * 4);    // NE
    float*    HS     = (float*)(wsb + (305152ull + NE) * 4);              // NN*64
    float*    X      = (float*)(wsb + (305152ull + NE + 6400000ull) * 4); // NN*64
    unsigned* ebuf   = (unsigned*)X;  // aliases X: used only before layer 1
    float*    G      = (float*)(wsb + (305152ull + NE + 12800000ull) * 4); // NN*8

    const int BLK = 256;
    const int gE  = (NE + BLK - 1) / BLK;
    const int gN  = (NN + BLK - 1) / BLK;
    const int gW  = (NN * 64 + BLK - 1) / BLK;     // wave-per-node
    auto gNF = [&](int f) { return (NN * f + BLK - 1) / BLK; };

    // ---- CSR build + dinv ----
    hipMemsetAsync(cnt, 0, NN * sizeof(int), stream);
    k_hist <<<gE, BLK, 0, stream>>>(dst, cnt);
    k_dinv <<<gN, BLK, 0, stream>>>(cnt, dinv);
    k_scan1<<<NBLK, SCAN_B, 0, stream>>>(cnt, rowp, bsum);
    k_scan2<<<1, 512, 0, stream>>>(bsum);
    k_scan3<<<gN, BLK, 0, stream>>>(rowp, bsum);
    k_bseed<<<(NBUK + BLK - 1) / BLK, BLK, 0, stream>>>(rowp, bcur);
    k_bucket<<<NCHUNK * NGRP, BLK, 0, stream>>>(src, dst, bcur, ebuf);
    k_fill2<<<NBUK, BLK, 0, stream>>>(ebuf, rowp, csr);

    // ---- Layer 1: gather at F_in=5 (pad 8), then 5->64 GEMM + BN + ReLU ----
    k_stage1<<<gNF(8), BLK, 0, stream>>>(x, dinv, HS);
    k_gather<8, 0><<<gW, BLK, 0, stream>>>(rowp, cnt, csr, HS, dinv,
                                           nullptr, nullptr, nullptr, nullptr, nullptr, G);
    k_lin1<<<gNF(64), BLK, 0, stream>>>(G, W1, b1, g1, be1, m1, v1, X);

    // ---- Layer 2: 64 -> 32 GEMM, gather at 32, BN + ReLU ----
    k_linear_scale<64, 32, 32><<<gNF(32), BLK, 0, stream>>>(X, W2, dinv, HS);
    k_gather<32, 2><<<gW, BLK, 0, stream>>>(rowp, cnt, csr, HS, dinv, b2, g2, be2, m2, v2, X);

    // ---- Layer 3: 32 -> 16 GEMM, gather at 16, ReLU ----
    k_linear_scale<32, 16, 16><<<gNF(16), BLK, 0, stream>>>(X, W3, dinv, HS);
    k_gather<16, 1><<<gW, BLK, 0, stream>>>(rowp, cnt, csr, HS, dinv, b3,
                                            nullptr, nullptr, nullptr, nullptr, X);

    // ---- Layer 4: 16 -> 3 GEMM (pad 4), gather at 4, logits ----
    k_linear_scale<16, 3, 4><<<gNF(4), BLK, 0, stream>>>(X, W4, dinv, HS);
    k_gather<4, 3><<<gW, BLK, 0, stream>>>(rowp, cnt, csr, HS, dinv, b4,
                                           nullptr, nullptr, nullptr, nullptr, out);
}

// Round 7
// 344.847 us; speedup vs baseline: 2.7146x; 2.7146x over previous
//
#include <hip/hip_runtime.h>

static constexpr int NN = 100000;   // nodes
static constexpr int NE = 3200000;  // edges
static constexpr float EPS = 1e-5f;
static constexpr int NB   = 391;    // coarse bins (dst>>8), 256 nodes each
static constexpr int CAP2 = 9216;   // bin capacity (mean 8192 + ~11 sigma)
static constexpr int CH1  = 8192;   // pass-1 edges per block
static constexpr int NBLK1 = (NE + CH1 - 1) / CH1;   // 391

// ---- seed per-bin global cursors to padded bin bases ---------------------
__global__ void k_seed(int* __restrict__ gcur) {
    int t = blockIdx.x * blockDim.x + threadIdx.x;
    if (t < NB) gcur[t] = t * CAP2;
}

// ---- pass 1: LDS counting-sort chunk into coarse bins, coalesced out -----
__global__ __launch_bounds__(256) void k_part1(const int* __restrict__ src,
                                               const int* __restrict__ dst,
                                               int* __restrict__ gcur,
                                               unsigned* __restrict__ ebuf) {
    __shared__ unsigned stage[CH1];
    __shared__ int hist[NB], lbase[NB + 1], lcur[NB], gbase[NB];
    int tid = threadIdx.x;
    int e0 = blockIdx.x * CH1;
    int n = min(CH1, NE - e0);

    for (int t = tid; t < NB; t += 256) { hist[t] = 0; lcur[t] = 0; }
    __syncthreads();
    for (int i = tid; i < n; i += 256) atomicAdd(&hist[dst[e0 + i] >> 8], 1);
    __syncthreads();
    for (int t = tid; t < NB; t += 256) gbase[t] = atomicAdd(&gcur[t], hist[t]);  // FIX: full NB coverage
    if (tid < 64) {                       // wave exclusive scan hist -> lbase
        int lane = tid, sum = 0, pre[7];
        #pragma unroll
        for (int k = 0; k < 7; ++k) {
            int idx = lane * 7 + k;
            int v = (idx < NB) ? hist[idx] : 0;
            pre[k] = sum; sum += v;
        }
        int inc = sum;
        #pragma unroll
        for (int off = 1; off < 64; off <<= 1) {
            int t = __shfl_up(inc, off);
            if (lane >= off) inc += t;
        }
        int excl = inc - sum;
        #pragma unroll
        for (int k = 0; k < 7; ++k) {
            int idx = lane * 7 + k;
            if (idx < NB + 1) lbase[idx] = excl + pre[k];
        }
    }
    __syncthreads();
    for (int i = tid; i < n; i += 256) {
        int d = dst[e0 + i];
        int b = d >> 8;
        int r = atomicAdd(&lcur[b], 1);
        stage[lbase[b] + r] = ((unsigned)(d & 255) << 17) | (unsigned)src[e0 + i];
    }
    __syncthreads();
    for (int i = tid; i < n; i += 256) {
        int lo = 0, hi = NB;              // largest b with lbase[b] <= i
        while (hi - lo > 1) { int mid = (lo + hi) >> 1; if (lbase[mid] <= i) lo = mid; else hi = mid; }
        ebuf[gbase[lo] + (i - lbase[lo])] = stage[i];
    }
}

// ---- exact bin-base scan (392 values) ------------------------------------
__global__ void k_binscan(const int* __restrict__ gcur, int* __restrict__ binBase) {
    __shared__ int s[512];
    int t = threadIdx.x;
    int v = (t < NB) ? (gcur[t] - t * CAP2) : 0;
    s[t] = v;
    __syncthreads();
    for (int off = 1; off < 512; off <<= 1) {
        int x = (t >= off) ? s[t - off] : 0;
        __syncthreads();
        s[t] += x;
        __syncthreads();
    }
    if (t < NB + 1) binBase[t] = s[t] - v;   // exclusive (v=0 for t==NB)
}

// ---- pass 2: fine sort bin -> CSR (LDS staging, coalesced out) -----------
// also emits rowp/cnt/dinv per node (replaces hist + 3 scan kernels)
__global__ __launch_bounds__(256) void k_part2(const unsigned* __restrict__ ebuf,
                                               const int* __restrict__ binBase,
                                               int* __restrict__ csr, int* __restrict__ rowp,
                                               int* __restrict__ cnt, float* __restrict__ dinv) {
    __shared__ unsigned s2[CAP2];
    __shared__ int lhist[256], lrow[257];
    int tid = threadIdx.x, b = blockIdx.x;
    int base = b * CAP2;
    int o0 = binBase[b], m = binBase[b + 1] - o0;

    lhist[tid] = 0;
    __syncthreads();
    for (int i = tid; i < m; i += 256) atomicAdd(&lhist[ebuf[base + i] >> 17], 1);
    __syncthreads();
    if (tid < 64) {                       // wave exclusive scan lhist -> lrow
        int lane = tid, sum = 0, pre[4];
        #pragma unroll
        for (int k = 0; k < 4; ++k) { pre[k] = sum; sum += lhist[lane * 4 + k]; }
        int inc = sum;
        #pragma unroll
        for (int off = 1; off < 64; off <<= 1) {
            int t = __shfl_up(inc, off);
            if (lane >= off) inc += t;
        }
        int excl = inc - sum;
        #pragma unroll
        for (int k = 0; k < 4; ++k) lrow[lane * 4 + k] = excl + pre[k];
        if (lane == 63) lrow[256] = excl + sum;
    }
    __syncthreads();
    lhist[tid] = 0;                       // reuse as cursor
    __syncthreads();
    for (int i = tid; i < m; i += 256) {
        unsigned p = ebuf[base + i];
        int nd = (int)(p >> 17);
        int r = atomicAdd(&lhist[nd], 1);
        s2[lrow[nd] + r] = p & 0x1FFFFu;
    }
    __syncthreads();
    for (int i = tid; i < m; i += 256) csr[o0 + i] = (int)s2[i];
    int ng = (b << 8) + tid;
    if (ng < NN) {
        int c = lrow[tid + 1] - lrow[tid];
        rowp[ng] = o0 + lrow[tid];
        cnt[ng] = c;
        dinv[ng] = rsqrtf((float)c + 1.f);
    }
}

// ---- layer-1 staging: q[i, 0..7] = dinv[i]*x[i, 0..4], pad 0 -------------
__global__ void k_stage1(const float* __restrict__ x, const float* __restrict__ dinv,
                         float* __restrict__ q) {
    int idx = blockIdx.x * blockDim.x + threadIdx.x;
    if (idx >= NN * 8) return;
    int i = idx >> 3, k = idx & 7;
    q[idx] = (k < 5) ? x[i * 5 + k] * dinv[i] : 0.f;
}

// ---- hs = dinv[i] * (in[i,:] @ W), OUTP-padded rows ----------------------
template<int IN, int OUT, int OUTP>
__global__ void k_linear_scale(const float* __restrict__ in, const float* __restrict__ W,
                               const float* __restrict__ dinv, float* __restrict__ hs) {
    int idx = blockIdx.x * blockDim.x + threadIdx.x;
    if (idx >= NN * OUTP) return;
    int i = idx / OUTP, f = idx - i * OUTP;
    float a = 0.f;
    if (f < OUT) {
        #pragma unroll
        for (int k = 0; k < IN; ++k) a += in[i * IN + k] * W[k * OUT + f];
        a *= dinv[i];
    }
    hs[idx] = a;
}

// ---- wave-per-node float4 gather + fused finalize -------------------------
// F = padded feature width (multiple of 4). MODE: 0 scale only (write F),
// 1 bias+relu, 2 bias+bn+relu, 3 bias only + write 3 floats (logits).
template<int F, int MODE>
__global__ void k_gather(const int* __restrict__ row_ptr, const int* __restrict__ cnt,
                         const int* __restrict__ csr, const float* __restrict__ hs,
                         const float* __restrict__ dinv, const float* __restrict__ b,
                         const float* __restrict__ g, const float* __restrict__ be,
                         const float* __restrict__ m, const float* __restrict__ vv,
                         float* __restrict__ out) {
    constexpr int F4  = F / 4;        // lanes per edge
    constexpr int EPI = 64 / F4;      // edges per iteration

    int node = (blockIdx.x * blockDim.x + threadIdx.x) >> 6;
    if (node >= NN) return;
    int lane = threadIdx.x & 63;
    int c = lane & (F4 - 1);          // float4 column within row
    int e = lane / F4;                // edge slot

    int start = row_ptr[node];
    int n     = cnt[node];

    float4 a  = make_float4(0.f, 0.f, 0.f, 0.f);
    float4 a2 = make_float4(0.f, 0.f, 0.f, 0.f);
    for (int j = e; j < n; j += 2 * EPI) {
        int s = csr[start + j];
        float4 v = reinterpret_cast<const float4*>(hs + (size_t)s * F)[c];
        int j2 = j + EPI;
        if (j2 < n) {
            int s2 = csr[start + j2];
            float4 v2 = reinterpret_cast<const float4*>(hs + (size_t)s2 * F)[c];
            a2.x += v2.x; a2.y += v2.y; a2.z += v2.z; a2.w += v2.w;
        }
        a.x += v.x; a.y += v.y; a.z += v.z; a.w += v.w;
    }
    a.x += a2.x; a.y += a2.y; a.z += a2.z; a.w += a2.w;
    #pragma unroll
    for (int mask = F4; mask < 64; mask <<= 1) {
        a.x += __shfl_xor(a.x, mask);
        a.y += __shfl_xor(a.y, mask);
        a.z += __shfl_xor(a.z, mask);
        a.w += __shfl_xor(a.w, mask);
    }

    if (lane < F4) {
        float4 self = reinterpret_cast<const float4*>(hs + (size_t)node * F)[lane];
        float di = dinv[node];
        float4 z;
        z.x = di * (a.x + self.x);
        z.y = di * (a.y + self.y);
        z.z = di * (a.z + self.z);
        z.w = di * (a.w + self.w);
        if constexpr (MODE >= 1) {
            int f0 = lane * 4;
            z.x += b[f0 + 0]; z.y += b[f0 + 1];
            z.z += b[f0 + 2]; z.w += (MODE == 3 ? 0.f : b[f0 + 3]);
            if constexpr (MODE == 2) {
                z.x = (z.x - m[f0+0]) * rsqrtf(vv[f0+0] + EPS) * g[f0+0] + be[f0+0];
                z.y = (z.y - m[f0+1]) * rsqrtf(vv[f0+1] + EPS) * g[f0+1] + be[f0+1];
                z.z = (z.z - m[f0+2]) * rsqrtf(vv[f0+2] + EPS) * g[f0+2] + be[f0+2];
                z.w = (z.w - m[f0+3]) * rsqrtf(vv[f0+3] + EPS) * g[f0+3] + be[f0+3];
            }
            if constexpr (MODE == 1 || MODE == 2) {
                z.x = fmaxf(z.x, 0.f); z.y = fmaxf(z.y, 0.f);
                z.z = fmaxf(z.z, 0.f); z.w = fmaxf(z.w, 0.f);
            }
        }
        if constexpr (MODE == 3) {
            float* o = out + (size_t)node * 3;
            o[0] = z.x; o[1] = z.y; o[2] = z.z;
        } else {
            reinterpret_cast<float4*>(out + (size_t)node * F)[lane] = z;
        }
    }
}

// ---- layer-1 tail: X1 = relu(bn(G[:, :5] @ W1 + b1)) ----------------------
__global__ void k_lin1(const float* __restrict__ G, const float* __restrict__ W1,
                       const float* __restrict__ b1, const float* __restrict__ g1,
                       const float* __restrict__ be1, const float* __restrict__ m1,
                       const float* __restrict__ v1, float* __restrict__ X) {
    int idx = blockIdx.x * blockDim.x + threadIdx.x;
    if (idx >= NN * 64) return;
    int i = idx >> 6, f = idx & 63;
    const float* gr = G + (size_t)i * 8;
    float z = b1[f];
    #pragma unroll
    for (int k = 0; k < 5; ++k) z += gr[k] * W1[k * 64 + f];
    z = (z - m1[f]) * rsqrtf(v1[f] + EPS) * g1[f] + be1[f];
    X[idx] = fmaxf(z, 0.f);
}

extern "C" void kernel_launch(void* const* d_in, const int* in_sizes, int n_in,
                              void* d_out, int out_size, void* d_ws, size_t ws_size,
                              hipStream_t stream) {
    const float* x   = (const float*)d_in[0];
    const int*   src = (const int*)  d_in[1];
    const int*   dst = (const int*)  d_in[2];
    const float* W1  = (const float*)d_in[3];
    const float* b1  = (const float*)d_in[4];
    const float* g1  = (const float*)d_in[5];
    const float* be1 = (const float*)d_in[6];
    const float* m1  = (const float*)d_in[7];
    const float* v1  = (const float*)d_in[8];
    const float* W2  = (const float*)d_in[9];
    const float* b2  = (const float*)d_in[10];
    const float* g2  = (const float*)d_in[11];
    const float* be2 = (const float*)d_in[12];
    const float* m2  = (const float*)d_in[13];
    const float* v2  = (const float*)d_in[14];
    const float* W3  = (const float*)d_in[15];
    const float* b3  = (const float*)d_in[16];
    const float* W4  = (const float*)d_in[17];
    const float* b4  = (const float*)d_in[18];
    float* out = (float*)d_out;

    // workspace layout (4-byte units)
    char* wsb = (char*)d_ws;
    float*    dinv    = (float*)wsb;                    // 100352
    int*      cnt     = (int*)(wsb + 100352ull * 4);    // 100352
    int*      rowp    = (int*)(wsb + 200704ull * 4);    // 100352
    int*      gcur    = (int*)(wsb + 301056ull * 4);    // 512
    int*      binBase = (int*)(wsb + 301568ull * 4);    // 512
    int*      csr     = (int*)(wsb + 302080ull * 4);    // NE
    float*    HS      = (float*)(wsb + (302080ull + NE) * 4);              // NN*64
    float*    X       = (float*)(wsb + (302080ull + NE + 6400000ull) * 4); // NN*64
    unsigned* ebuf    = (unsigned*)X;  // aliases X (NB*CAP2 = 3.6M <= 6.4M); X written after part2
    float*    G       = (float*)(wsb + (302080ull + NE + 12800000ull) * 4); // NN*8

    const int BLK = 256;
    const int gW  = (NN * 64 + BLK - 1) / BLK;     // wave-per-node
    auto gNF = [&](int f) { return (NN * f + BLK - 1) / BLK; };

    // ---- CSR build (2-pass LDS counting sort) + per-node rowp/cnt/dinv ----
    k_seed   <<<2, 256, 0, stream>>>(gcur);
    k_part1  <<<NBLK1, BLK, 0, stream>>>(src, dst, gcur, ebuf);
    k_binscan<<<1, 512, 0, stream>>>(gcur, binBase);
    k_part2  <<<NB, BLK, 0, stream>>>(ebuf, binBase, csr, rowp, cnt, dinv);

    // ---- Layer 1: gather at F_in=5 (pad 8), then 5->64 GEMM + BN + ReLU ----
    k_stage1<<<gNF(8), BLK, 0, stream>>>(x, dinv, HS);
    k_gather<8, 0><<<gW, BLK, 0, stream>>>(rowp, cnt, csr, HS, dinv,
                                           nullptr, nullptr, nullptr, nullptr, nullptr, G);
    k_lin1<<<gNF(64), BLK, 0, stream>>>(G, W1, b1, g1, be1, m1, v1, X);

    // ---- Layer 2: 64 -> 32 GEMM, gather at 32, BN + ReLU ----
    k_linear_scale<64, 32, 32><<<gNF(32), BLK, 0, stream>>>(X, W2, dinv, HS);
    k_gather<32, 2><<<gW, BLK, 0, stream>>>(rowp, cnt, csr, HS, dinv, b2, g2, be2, m2, v2, X);

    // ---- Layer 3: 32 -> 16 GEMM, gather at 16, ReLU ----
    k_linear_scale<32, 16, 16><<<gNF(16), BLK, 0, stream>>>(X, W3, dinv, HS);
    k_gather<16, 1><<<gW, BLK, 0, stream>>>(rowp, cnt, csr, HS, dinv, b3,
                                            nullptr, nullptr, nullptr, nullptr, X);

    // ---- Layer 4: 16 -> 3 GEMM (pad 4), gather at 4, logits ----
    k_linear_scale<16, 3, 4><<<gNF(4), BLK, 0, stream>>>(X, W4, dinv, HS);
    k_gather<4, 3><<<gW, BLK, 0, stream>>>(rowp, cnt, csr, HS, dinv, b4,
                                           nullptr, nullptr, nullptr, nullptr, out);
}

// Round 8
// 327.085 us; speedup vs baseline: 2.8620x; 1.0543x over previous
//
#include <hip/hip_runtime.h>
#include <hip/hip_fp16.h>

static constexpr int NN = 100000;   // nodes
static constexpr int NE = 3200000;  // edges
static constexpr float EPS = 1e-5f;
static constexpr int NB   = 391;    // coarse bins (dst>>8), 256 nodes each
static constexpr int CAP2 = 9216;   // bin capacity (mean 8192 + ~11 sigma)
static constexpr int CH1  = 4096;   // pass-1 edges per block (782 blocks: occupancy)
static constexpr int NBLK1 = (NE + CH1 - 1) / CH1;   // 782

// ---- seed per-bin global cursors to padded bin bases ---------------------
__global__ void k_seed(int* __restrict__ gcur) {
    int t = blockIdx.x * blockDim.x + threadIdx.x;
    if (t < NB) gcur[t] = t * CAP2;
}

// ---- pass 1: LDS counting-sort chunk into coarse bins, coalesced out -----
__global__ __launch_bounds__(256) void k_part1(const int* __restrict__ src,
                                               const int* __restrict__ dst,
                                               int* __restrict__ gcur,
                                               unsigned* __restrict__ ebuf) {
    __shared__ unsigned stage[CH1];
    __shared__ int hist[NB], lbase[NB + 1], lcur[NB], gbase[NB];
    int tid = threadIdx.x;
    int e0 = blockIdx.x * CH1;
    int n = min(CH1, NE - e0);

    for (int t = tid; t < NB; t += 256) { hist[t] = 0; lcur[t] = 0; }
    __syncthreads();
    for (int i = tid; i < n; i += 256) atomicAdd(&hist[dst[e0 + i] >> 8], 1);
    __syncthreads();
    for (int t = tid; t < NB; t += 256) gbase[t] = atomicAdd(&gcur[t], hist[t]);
    if (tid < 64) {                       // wave exclusive scan hist -> lbase
        int lane = tid, sum = 0, pre[7];
        #pragma unroll
        for (int k = 0; k < 7; ++k) {
            int idx = lane * 7 + k;
            int v = (idx < NB) ? hist[idx] : 0;
            pre[k] = sum; sum += v;
        }
        int inc = sum;
        #pragma unroll
        for (int off = 1; off < 64; off <<= 1) {
            int t = __shfl_up(inc, off);
            if (lane >= off) inc += t;
        }
        int excl = inc - sum;
        #pragma unroll
        for (int k = 0; k < 7; ++k) {
            int idx = lane * 7 + k;
            if (idx < NB + 1) lbase[idx] = excl + pre[k];
        }
    }
    __syncthreads();
    for (int i = tid; i < n; i += 256) {
        int d = dst[e0 + i];
        int b = d >> 8;
        int r = atomicAdd(&lcur[b], 1);
        stage[lbase[b] + r] = ((unsigned)(d & 255) << 17) | (unsigned)src[e0 + i];
    }
    __syncthreads();
    for (int i = tid; i < n; i += 256) {
        int lo = 0, hi = NB;              // largest b with lbase[b] <= i
        while (hi - lo > 1) { int mid = (lo + hi) >> 1; if (lbase[mid] <= i) lo = mid; else hi = mid; }
        ebuf[gbase[lo] + (i - lbase[lo])] = stage[i];
    }
}

// ---- exact bin-base scan (392 values) ------------------------------------
__global__ void k_binscan(const int* __restrict__ gcur, int* __restrict__ binBase) {
    __shared__ int s[512];
    int t = threadIdx.x;
    int v = (t < NB) ? (gcur[t] - t * CAP2) : 0;
    s[t] = v;
    __syncthreads();
    for (int off = 1; off < 512; off <<= 1) {
        int x = (t >= off) ? s[t - off] : 0;
        __syncthreads();
        s[t] += x;
        __syncthreads();
    }
    if (t < NB + 1) binBase[t] = s[t] - v;   // exclusive (v=0 for t==NB)
}

// ---- pass 2: fine sort bin -> CSR (LDS staging, coalesced out) -----------
__global__ __launch_bounds__(256) void k_part2(const unsigned* __restrict__ ebuf,
                                               const int* __restrict__ binBase,
                                               int* __restrict__ csr, int* __restrict__ rowp,
                                               int* __restrict__ cnt, float* __restrict__ dinv) {
    __shared__ unsigned s2[CAP2];
    __shared__ int lhist[256], lrow[257];
    int tid = threadIdx.x, b = blockIdx.x;
    int base = b * CAP2;
    int o0 = binBase[b], m = binBase[b + 1] - o0;

    lhist[tid] = 0;
    __syncthreads();
    for (int i = tid; i < m; i += 256) atomicAdd(&lhist[ebuf[base + i] >> 17], 1);
    __syncthreads();
    if (tid < 64) {                       // wave exclusive scan lhist -> lrow
        int lane = tid, sum = 0, pre[4];
        #pragma unroll
        for (int k = 0; k < 4; ++k) { pre[k] = sum; sum += lhist[lane * 4 + k]; }
        int inc = sum;
        #pragma unroll
        for (int off = 1; off < 64; off <<= 1) {
            int t = __shfl_up(inc, off);
            if (lane >= off) inc += t;
        }
        int excl = inc - sum;
        #pragma unroll
        for (int k = 0; k < 4; ++k) lrow[lane * 4 + k] = excl + pre[k];
        if (lane == 63) lrow[256] = excl + sum;
    }
    __syncthreads();
    lhist[tid] = 0;                       // reuse as cursor
    __syncthreads();
    for (int i = tid; i < m; i += 256) {
        unsigned p = ebuf[base + i];
        int nd = (int)(p >> 17);
        int r = atomicAdd(&lhist[nd], 1);
        s2[lrow[nd] + r] = p & 0x1FFFFu;
    }
    __syncthreads();
    for (int i = tid; i < m; i += 256) csr[o0 + i] = (int)s2[i];
    int ng = (b << 8) + tid;
    if (ng < NN) {
        int c = lrow[tid + 1] - lrow[tid];
        rowp[ng] = o0 + lrow[tid];
        cnt[ng] = c;
        dinv[ng] = rsqrtf((float)c + 1.f);
    }
}

// ---- layer-1 staging: q[i, 0..7] = dinv[i]*x[i, 0..4], pad 0 -------------
__global__ void k_stage1(const float* __restrict__ x, const float* __restrict__ dinv,
                         float* __restrict__ q) {
    int idx = blockIdx.x * blockDim.x + threadIdx.x;
    if (idx >= NN * 8) return;
    int i = idx >> 3, k = idx & 7;
    q[idx] = (k < 5) ? x[i * 5 + k] * dinv[i] : 0.f;
}

// ---- hs(f32) = dinv[i] * (in[i,:] @ W), OUTP-padded rows -----------------
template<int IN, int OUT, int OUTP>
__global__ void k_linear_scale(const float* __restrict__ in, const float* __restrict__ W,
                               const float* __restrict__ dinv, float* __restrict__ hs) {
    int idx = blockIdx.x * blockDim.x + threadIdx.x;
    if (idx >= NN * OUTP) return;
    int i = idx / OUTP, f = idx - i * OUTP;
    float a = 0.f;
    if (f < OUT) {
        #pragma unroll
        for (int k = 0; k < IN; ++k) a += in[i * IN + k] * W[k * OUT + f];
        a *= dinv[i];
    }
    hs[idx] = a;
}

// ---- hs(f16) = dinv[i] * (in[i,:] @ W) -----------------------------------
template<int IN, int OUT>
__global__ void k_linear_scale_h(const float* __restrict__ in, const float* __restrict__ W,
                                 const float* __restrict__ dinv, __half* __restrict__ hs) {
    int idx = blockIdx.x * blockDim.x + threadIdx.x;
    if (idx >= NN * OUT) return;
    int i = idx / OUT, f = idx - i * OUT;
    float a = 0.f;
    #pragma unroll
    for (int k = 0; k < IN; ++k) a += in[i * IN + k] * W[k * OUT + f];
    hs[idx] = __float2half(a * dinv[i]);
}

// ---- f32 wave-per-node float4 gather + fused finalize ---------------------
// MODE: 0 scale only (write F), 3 bias only + write 3 floats (logits).
template<int F, int MODE>
__global__ void k_gather(const int* __restrict__ row_ptr, const int* __restrict__ cnt,
                         const int* __restrict__ csr, const float* __restrict__ hs,
                         const float* __restrict__ dinv, const float* __restrict__ b,
                         float* __restrict__ out) {
    constexpr int F4  = F / 4;
    constexpr int EPI = 64 / F4;

    int node = (blockIdx.x * blockDim.x + threadIdx.x) >> 6;
    if (node >= NN) return;
    int lane = threadIdx.x & 63;
    int c = lane & (F4 - 1);
    int e = lane / F4;

    int start = row_ptr[node];
    int n     = cnt[node];

    float4 a  = make_float4(0.f, 0.f, 0.f, 0.f);
    float4 a2 = make_float4(0.f, 0.f, 0.f, 0.f);
    for (int j = e; j < n; j += 2 * EPI) {
        int s = csr[start + j];
        float4 v = reinterpret_cast<const float4*>(hs + (size_t)s * F)[c];
        int j2 = j + EPI;
        if (j2 < n) {
            int s2 = csr[start + j2];
            float4 v2 = reinterpret_cast<const float4*>(hs + (size_t)s2 * F)[c];
            a2.x += v2.x; a2.y += v2.y; a2.z += v2.z; a2.w += v2.w;
        }
        a.x += v.x; a.y += v.y; a.z += v.z; a.w += v.w;
    }
    a.x += a2.x; a.y += a2.y; a.z += a2.z; a.w += a2.w;
    #pragma unroll
    for (int mask = F4; mask < 64; mask <<= 1) {
        a.x += __shfl_xor(a.x, mask);
        a.y += __shfl_xor(a.y, mask);
        a.z += __shfl_xor(a.z, mask);
        a.w += __shfl_xor(a.w, mask);
    }

    if (lane < F4) {
        float4 self = reinterpret_cast<const float4*>(hs + (size_t)node * F)[lane];
        float di = dinv[node];
        float4 z;
        z.x = di * (a.x + self.x);
        z.y = di * (a.y + self.y);
        z.z = di * (a.z + self.z);
        z.w = di * (a.w + self.w);
        if constexpr (MODE == 3) {
            float* o = out + (size_t)node * 3;
            o[0] = z.x + b[0]; o[1] = z.y + b[1]; o[2] = z.z + b[2];
        } else {
            reinterpret_cast<float4*>(out + (size_t)node * F)[lane] = z;
        }
    }
}

// ---- f16 wave-per-node gather (8B/lane) + fused finalize ------------------
// MODE: 1 bias+relu, 2 bias+bn+relu. Output f32.
template<int F, int MODE>
__global__ void k_gather_h(const int* __restrict__ row_ptr, const int* __restrict__ cnt,
                           const int* __restrict__ csr, const __half* __restrict__ hs,
                           const float* __restrict__ dinv, const float* __restrict__ b,
                           const float* __restrict__ g, const float* __restrict__ be,
                           const float* __restrict__ m, const float* __restrict__ vv,
                           float* __restrict__ out) {
    constexpr int F4  = F / 4;        // lanes per edge (4 halves = 8B per lane)
    constexpr int EPI = 64 / F4;

    int node = (blockIdx.x * blockDim.x + threadIdx.x) >> 6;
    if (node >= NN) return;
    int lane = threadIdx.x & 63;
    int c = lane & (F4 - 1);
    int e = lane / F4;

    int start = row_ptr[node];
    int n     = cnt[node];

    float4 a  = make_float4(0.f, 0.f, 0.f, 0.f);
    float4 a2 = make_float4(0.f, 0.f, 0.f, 0.f);
    for (int j = e; j < n; j += 2 * EPI) {
        int s = csr[start + j];
        uint2 r = reinterpret_cast<const uint2*>(hs + (size_t)s * F)[c];
        int j2 = j + EPI;
        if (j2 < n) {
            int s2 = csr[start + j2];
            uint2 r2 = reinterpret_cast<const uint2*>(hs + (size_t)s2 * F)[c];
            float2 f0 = __half22float2(*reinterpret_cast<__half2*>(&r2.x));
            float2 f1 = __half22float2(*reinterpret_cast<__half2*>(&r2.y));
            a2.x += f0.x; a2.y += f0.y; a2.z += f1.x; a2.w += f1.y;
        }
        float2 f0 = __half22float2(*reinterpret_cast<__half2*>(&r.x));
        float2 f1 = __half22float2(*reinterpret_cast<__half2*>(&r.y));
        a.x += f0.x; a.y += f0.y; a.z += f1.x; a.w += f1.y;
    }
    a.x += a2.x; a.y += a2.y; a.z += a2.z; a.w += a2.w;
    #pragma unroll
    for (int mask = F4; mask < 64; mask <<= 1) {
        a.x += __shfl_xor(a.x, mask);
        a.y += __shfl_xor(a.y, mask);
        a.z += __shfl_xor(a.z, mask);
        a.w += __shfl_xor(a.w, mask);
    }

    if (lane < F4) {
        uint2 r = reinterpret_cast<const uint2*>(hs + (size_t)node * F)[lane];
        float2 s0 = __half22float2(*reinterpret_cast<__half2*>(&r.x));
        float2 s1 = __half22float2(*reinterpret_cast<__half2*>(&r.y));
        float di = dinv[node];
        int f0 = lane * 4;
        float4 z;
        z.x = di * (a.x + s0.x) + b[f0 + 0];
        z.y = di * (a.y + s0.y) + b[f0 + 1];
        z.z = di * (a.z + s1.x) + b[f0 + 2];
        z.w = di * (a.w + s1.y) + b[f0 + 3];
        if constexpr (MODE == 2) {
            z.x = (z.x - m[f0+0]) * rsqrtf(vv[f0+0] + EPS) * g[f0+0] + be[f0+0];
            z.y = (z.y - m[f0+1]) * rsqrtf(vv[f0+1] + EPS) * g[f0+1] + be[f0+1];
            z.z = (z.z - m[f0+2]) * rsqrtf(vv[f0+2] + EPS) * g[f0+2] + be[f0+2];
            z.w = (z.w - m[f0+3]) * rsqrtf(vv[f0+3] + EPS) * g[f0+3] + be[f0+3];
        }
        z.x = fmaxf(z.x, 0.f); z.y = fmaxf(z.y, 0.f);
        z.z = fmaxf(z.z, 0.f); z.w = fmaxf(z.w, 0.f);
        reinterpret_cast<float4*>(out + (size_t)node * F)[lane] = z;
    }
}

// ---- layer-1 tail: X1 = relu(bn(G[:, :5] @ W1 + b1)) ----------------------
__global__ void k_lin1(const float* __restrict__ G, const float* __restrict__ W1,
                       const float* __restrict__ b1, const float* __restrict__ g1,
                       const float* __restrict__ be1, const float* __restrict__ m1,
                       const float* __restrict__ v1, float* __restrict__ X) {
    int idx = blockIdx.x * blockDim.x + threadIdx.x;
    if (idx >= NN * 64) return;
    int i = idx >> 6, f = idx & 63;
    const float* gr = G + (size_t)i * 8;
    float z = b1[f];
    #pragma unroll
    for (int k = 0; k < 5; ++k) z += gr[k] * W1[k * 64 + f];
    z = (z - m1[f]) * rsqrtf(v1[f] + EPS) * g1[f] + be1[f];
    X[idx] = fmaxf(z, 0.f);
}

extern "C" void kernel_launch(void* const* d_in, const int* in_sizes, int n_in,
                              void* d_out, int out_size, void* d_ws, size_t ws_size,
                              hipStream_t stream) {
    const float* x   = (const float*)d_in[0];
    const int*   src = (const int*)  d_in[1];
    const int*   dst = (const int*)  d_in[2];
    const float* W1  = (const float*)d_in[3];
    const float* b1  = (const float*)d_in[4];
    const float* g1  = (const float*)d_in[5];
    const float* be1 = (const float*)d_in[6];
    const float* m1  = (const float*)d_in[7];
    const float* v1  = (const float*)d_in[8];
    const float* W2  = (const float*)d_in[9];
    const float* b2  = (const float*)d_in[10];
    const float* g2  = (const float*)d_in[11];
    const float* be2 = (const float*)d_in[12];
    const float* m2  = (const float*)d_in[13];
    const float* v2  = (const float*)d_in[14];
    const float* W3  = (const float*)d_in[15];
    const float* b3  = (const float*)d_in[16];
    const float* W4  = (const float*)d_in[17];
    const float* b4  = (const float*)d_in[18];
    float* out = (float*)d_out;

    // workspace layout (4-byte units)
    char* wsb = (char*)d_ws;
    float*    dinv    = (float*)wsb;                    // 100352
    int*      cnt     = (int*)(wsb + 100352ull * 4);    // 100352
    int*      rowp    = (int*)(wsb + 200704ull * 4);    // 100352
    int*      gcur    = (int*)(wsb + 301056ull * 4);    // 512
    int*      binBase = (int*)(wsb + 301568ull * 4);    // 512
    int*      csr     = (int*)(wsb + 302080ull * 4);    // NE
    float*    HS      = (float*)(wsb + (302080ull + NE) * 4);              // NN*64 f32
    __half*   HSh     = (__half*)HS;                                        // f16 view
    float*    X       = (float*)(wsb + (302080ull + NE + 6400000ull) * 4); // NN*64
    unsigned* ebuf    = (unsigned*)X;  // aliases X (NB*CAP2 = 3.6M <= 6.4M)
    float*    G       = (float*)(wsb + (302080ull + NE + 12800000ull) * 4); // NN*8

    const int BLK = 256;
    const int gW  = (NN * 64 + BLK - 1) / BLK;     // wave-per-node
    auto gNF = [&](int f) { return (NN * f + BLK - 1) / BLK; };

    // ---- CSR build (2-pass LDS counting sort) + per-node rowp/cnt/dinv ----
    k_seed   <<<2, 256, 0, stream>>>(gcur);
    k_part1  <<<NBLK1, BLK, 0, stream>>>(src, dst, gcur, ebuf);
    k_binscan<<<1, 512, 0, stream>>>(gcur, binBase);
    k_part2  <<<NB, BLK, 0, stream>>>(ebuf, binBase, csr, rowp, cnt, dinv);

    // ---- Layer 1: gather at F_in=5 (pad 8, f32), then 5->64 GEMM+BN+ReLU ----
    k_stage1<<<gNF(8), BLK, 0, stream>>>(x, dinv, HS);
    k_gather<8, 0><<<gW, BLK, 0, stream>>>(rowp, cnt, csr, HS, dinv, nullptr, G);
    k_lin1<<<gNF(64), BLK, 0, stream>>>(G, W1, b1, g1, be1, m1, v1, X);

    // ---- Layer 2: 64 -> 32 GEMM (f16 hs), gather_h at 32, BN + ReLU ----
    k_linear_scale_h<64, 32><<<gNF(32), BLK, 0, stream>>>(X, W2, dinv, HSh);
    k_gather_h<32, 2><<<gW, BLK, 0, stream>>>(rowp, cnt, csr, HSh, dinv, b2, g2, be2, m2, v2, X);

    // ---- Layer 3: 32 -> 16 GEMM (f16 hs), gather_h at 16, ReLU ----
    k_linear_scale_h<32, 16><<<gNF(16), BLK, 0, stream>>>(X, W3, dinv, HSh);
    k_gather_h<16, 1><<<gW, BLK, 0, stream>>>(rowp, cnt, csr, HSh, dinv, b3,
                                              nullptr, nullptr, nullptr, nullptr, X);

    // ---- Layer 4: 16 -> 3 GEMM (pad 4, f32), gather at 4, logits ----
    k_linear_scale<16, 3, 4><<<gNF(4), BLK, 0, stream>>>(X, W4, dinv, HS);
    k_gather<4, 3><<<gW, BLK, 0, stream>>>(rowp, cnt, csr, HS, dinv, b4, out);
}

// Round 9
// 317.282 us; speedup vs baseline: 2.9504x; 1.0309x over previous
//
#include <hip/hip_runtime.h>
#include <hip/hip_fp16.h>

static constexpr int NN = 100000;   // nodes
static constexpr int NE = 3200000;  // edges
static constexpr float EPS = 1e-5f;
static constexpr int NB   = 391;    // coarse bins (dst>>8), 256 nodes each
static constexpr int CAP2 = 9216;   // bin capacity (mean 8192 + ~11 sigma)
static constexpr int CH1  = 4096;   // pass-1 edges per block (782 blocks)
static constexpr int NBLK1 = (NE + CH1 - 1) / CH1;   // 782

// ---- seed per-bin global cursors to padded bin bases ---------------------
__global__ void k_seed(int* __restrict__ gcur) {
    int t = blockIdx.x * blockDim.x + threadIdx.x;
    if (t < NB) gcur[t] = t * CAP2;
}

// ---- pass 1: LDS counting-sort chunk into coarse bins, coalesced out -----
__global__ __launch_bounds__(256) void k_part1(const int* __restrict__ src,
                                               const int* __restrict__ dst,
                                               int* __restrict__ gcur,
                                               unsigned* __restrict__ ebuf) {
    __shared__ unsigned stage[CH1];
    __shared__ int hist[NB], lbase[NB + 1], lcur[NB], gbase[NB];
    int tid = threadIdx.x;
    int e0 = blockIdx.x * CH1;
    int n = min(CH1, NE - e0);

    for (int t = tid; t < NB; t += 256) { hist[t] = 0; lcur[t] = 0; }
    __syncthreads();
    for (int i = tid; i < n; i += 256) atomicAdd(&hist[dst[e0 + i] >> 8], 1);
    __syncthreads();
    for (int t = tid; t < NB; t += 256) gbase[t] = atomicAdd(&gcur[t], hist[t]);
    if (tid < 64) {                       // wave exclusive scan hist -> lbase
        int lane = tid, sum = 0, pre[7];
        #pragma unroll
        for (int k = 0; k < 7; ++k) {
            int idx = lane * 7 + k;
            int v = (idx < NB) ? hist[idx] : 0;
            pre[k] = sum; sum += v;
        }
        int inc = sum;
        #pragma unroll
        for (int off = 1; off < 64; off <<= 1) {
            int t = __shfl_up(inc, off);
            if (lane >= off) inc += t;
        }
        int excl = inc - sum;
        #pragma unroll
        for (int k = 0; k < 7; ++k) {
            int idx = lane * 7 + k;
            if (idx < NB + 1) lbase[idx] = excl + pre[k];
        }
    }
    __syncthreads();
    for (int i = tid; i < n; i += 256) {
        int d = dst[e0 + i];
        int b = d >> 8;
        int r = atomicAdd(&lcur[b], 1);
        stage[lbase[b] + r] = ((unsigned)(d & 255) << 17) | (unsigned)src[e0 + i];
    }
    __syncthreads();
    for (int i = tid; i < n; i += 256) {
        int lo = 0, hi = NB;              // largest b with lbase[b] <= i
        while (hi - lo > 1) { int mid = (lo + hi) >> 1; if (lbase[mid] <= i) lo = mid; else hi = mid; }
        ebuf[gbase[lo] + (i - lbase[lo])] = stage[i];
    }
}

// ---- exact bin-base scan (392 values) ------------------------------------
__global__ void k_binscan(const int* __restrict__ gcur, int* __restrict__ binBase) {
    __shared__ int s[512];
    int t = threadIdx.x;
    int v = (t < NB) ? (gcur[t] - t * CAP2) : 0;
    s[t] = v;
    __syncthreads();
    for (int off = 1; off < 512; off <<= 1) {
        int x = (t >= off) ? s[t - off] : 0;
        __syncthreads();
        s[t] += x;
        __syncthreads();
    }
    if (t < NB + 1) binBase[t] = s[t] - v;   // exclusive (v=0 for t==NB)
}

// ---- pass 2: fine sort bin -> CSR (LDS staging, coalesced out) -----------
__global__ __launch_bounds__(256) void k_part2(const unsigned* __restrict__ ebuf,
                                               const int* __restrict__ binBase,
                                               int* __restrict__ csr, int* __restrict__ rowp,
                                               int* __restrict__ cnt, float* __restrict__ dinv) {
    __shared__ unsigned s2[CAP2];
    __shared__ int lhist[256], lrow[257];
    int tid = threadIdx.x, b = blockIdx.x;
    int base = b * CAP2;
    int o0 = binBase[b], m = binBase[b + 1] - o0;

    lhist[tid] = 0;
    __syncthreads();
    for (int i = tid; i < m; i += 256) atomicAdd(&lhist[ebuf[base + i] >> 17], 1);
    __syncthreads();
    if (tid < 64) {                       // wave exclusive scan lhist -> lrow
        int lane = tid, sum = 0, pre[4];
        #pragma unroll
        for (int k = 0; k < 4; ++k) { pre[k] = sum; sum += lhist[lane * 4 + k]; }
        int inc = sum;
        #pragma unroll
        for (int off = 1; off < 64; off <<= 1) {
            int t = __shfl_up(inc, off);
            if (lane >= off) inc += t;
        }
        int excl = inc - sum;
        #pragma unroll
        for (int k = 0; k < 4; ++k) lrow[lane * 4 + k] = excl + pre[k];
        if (lane == 63) lrow[256] = excl + sum;
    }
    __syncthreads();
    lhist[tid] = 0;                       // reuse as cursor
    __syncthreads();
    for (int i = tid; i < m; i += 256) {
        unsigned p = ebuf[base + i];
        int nd = (int)(p >> 17);
        int r = atomicAdd(&lhist[nd], 1);
        s2[lrow[nd] + r] = p & 0x1FFFFu;
    }
    __syncthreads();
    for (int i = tid; i < m; i += 256) csr[o0 + i] = (int)s2[i];
    int ng = (b << 8) + tid;
    if (ng < NN) {
        int c = lrow[tid + 1] - lrow[tid];
        rowp[ng] = o0 + lrow[tid];
        cnt[ng] = c;
        dinv[ng] = rsqrtf((float)c + 1.f);
    }
}

// ---- layer-1 staging: q[i, 0..7] = dinv[i]*x[i, 0..4], pad 0 -------------
__global__ void k_stage1(const float* __restrict__ x, const float* __restrict__ dinv,
                         float* __restrict__ q) {
    int idx = blockIdx.x * blockDim.x + threadIdx.x;
    if (idx >= NN * 8) return;
    int i = idx >> 3, k = idx & 7;
    q[idx] = (k < 5) ? x[i * 5 + k] * dinv[i] : 0.f;
}

// ---- hs(f32) = dinv[i] * (in[i,:] @ W), OUTP-padded rows -----------------
template<int IN, int OUT, int OUTP>
__global__ void k_linear_scale(const float* __restrict__ in, const float* __restrict__ W,
                               const float* __restrict__ dinv, float* __restrict__ hs) {
    int idx = blockIdx.x * blockDim.x + threadIdx.x;
    if (idx >= NN * OUTP) return;
    int i = idx / OUTP, f = idx - i * OUTP;
    float a = 0.f;
    if (f < OUT) {
        #pragma unroll
        for (int k = 0; k < IN; ++k) a += in[i * IN + k] * W[k * OUT + f];
        a *= dinv[i];
    }
    hs[idx] = a;
}

// ---- hs(f16) = dinv[i] * (in[i,:] @ W) -----------------------------------
template<int IN, int OUT>
__global__ void k_linear_scale_h(const float* __restrict__ in, const float* __restrict__ W,
                                 const float* __restrict__ dinv, __half* __restrict__ hs) {
    int idx = blockIdx.x * blockDim.x + threadIdx.x;
    if (idx >= NN * OUT) return;
    int i = idx / OUT, f = idx - i * OUT;
    float a = 0.f;
    #pragma unroll
    for (int k = 0; k < IN; ++k) a += in[i * IN + k] * W[k * OUT + f];
    hs[idx] = __float2half(a * dinv[i]);
}

// ---- f32 gather: cooperative csr + shfl broadcast + clustered loads ------
// MODE: 0 scale only (write F), 3 bias only + write 3 floats (logits).
template<int F, int MODE>
__global__ __launch_bounds__(256) void k_gather(
        const int* __restrict__ row_ptr, const int* __restrict__ cnt,
        const int* __restrict__ csr, const float* __restrict__ hs,
        const float* __restrict__ dinv, const float* __restrict__ b,
        float* __restrict__ out) {
    constexpr int F4   = F / 4;       // lanes per edge (float4 each)
    constexpr int EPI  = 64 / F4;     // edges per iteration
    constexpr int ITER = F4;          // iterations per 64-edge chunk

    int node = (blockIdx.x * blockDim.x + threadIdx.x) >> 6;
    if (node >= NN) return;
    int lane = threadIdx.x & 63;
    int c = lane & (F4 - 1);
    int e = lane / F4;

    int start = row_ptr[node];
    int n     = cnt[node];

    float4 a = make_float4(0.f, 0.f, 0.f, 0.f);
    for (int base = 0; base < n; base += 64) {
        int rem = n - base;
        int my = (lane < rem) ? csr[start + base + lane] : 0;
        int s[ITER]; bool act[ITER];
        #pragma unroll
        for (int k = 0; k < ITER; ++k) {
            int j = e + k * EPI;
            int t = __shfl(my, j);
            act[k] = (j < rem);
            s[k] = act[k] ? t : 0;
        }
        float4 v[ITER];
        #pragma unroll
        for (int k = 0; k < ITER; ++k)
            v[k] = reinterpret_cast<const float4*>(hs + (size_t)s[k] * F)[c];
        #pragma unroll
        for (int k = 0; k < ITER; ++k)
            if (act[k]) { a.x += v[k].x; a.y += v[k].y; a.z += v[k].z; a.w += v[k].w; }
    }
    #pragma unroll
    for (int mask = F4; mask < 64; mask <<= 1) {
        a.x += __shfl_xor(a.x, mask);
        a.y += __shfl_xor(a.y, mask);
        a.z += __shfl_xor(a.z, mask);
        a.w += __shfl_xor(a.w, mask);
    }

    if (lane < F4) {
        float4 self = reinterpret_cast<const float4*>(hs + (size_t)node * F)[lane];
        float di = dinv[node];
        float4 z;
        z.x = di * (a.x + self.x);
        z.y = di * (a.y + self.y);
        z.z = di * (a.z + self.z);
        z.w = di * (a.w + self.w);
        if constexpr (MODE == 3) {
            float* o = out + (size_t)node * 3;
            o[0] = z.x + b[0]; o[1] = z.y + b[1]; o[2] = z.z + b[2];
        } else {
            reinterpret_cast<float4*>(out + (size_t)node * F)[lane] = z;
        }
    }
}

// ---- f16 gather (8B/lane): cooperative csr + clustered loads --------------
// MODE: 1 bias+relu, 2 bias+bn+relu. Output f32.
template<int F, int MODE>
__global__ __launch_bounds__(256) void k_gather_h(
        const int* __restrict__ row_ptr, const int* __restrict__ cnt,
        const int* __restrict__ csr, const __half* __restrict__ hs,
        const float* __restrict__ dinv, const float* __restrict__ b,
        const float* __restrict__ g, const float* __restrict__ be,
        const float* __restrict__ m, const float* __restrict__ vv,
        float* __restrict__ out) {
    constexpr int F4   = F / 4;       // lanes per edge (4 halves = 8B each)
    constexpr int EPI  = 64 / F4;
    constexpr int ITER = F4;

    int node = (blockIdx.x * blockDim.x + threadIdx.x) >> 6;
    if (node >= NN) return;
    int lane = threadIdx.x & 63;
    int c = lane & (F4 - 1);
    int e = lane / F4;

    int start = row_ptr[node];
    int n     = cnt[node];

    float4 a = make_float4(0.f, 0.f, 0.f, 0.f);
    for (int base = 0; base < n; base += 64) {
        int rem = n - base;
        int my = (lane < rem) ? csr[start + base + lane] : 0;
        int s[ITER]; bool act[ITER];
        #pragma unroll
        for (int k = 0; k < ITER; ++k) {
            int j = e + k * EPI;
            int t = __shfl(my, j);
            act[k] = (j < rem);
            s[k] = act[k] ? t : 0;
        }
        uint2 r[ITER];
        #pragma unroll
        for (int k = 0; k < ITER; ++k)
            r[k] = reinterpret_cast<const uint2*>(hs + (size_t)s[k] * F)[c];
        #pragma unroll
        for (int k = 0; k < ITER; ++k) {
            if (act[k]) {
                float2 f0 = __half22float2(*reinterpret_cast<__half2*>(&r[k].x));
                float2 f1 = __half22float2(*reinterpret_cast<__half2*>(&r[k].y));
                a.x += f0.x; a.y += f0.y; a.z += f1.x; a.w += f1.y;
            }
        }
    }
    #pragma unroll
    for (int mask = F4; mask < 64; mask <<= 1) {
        a.x += __shfl_xor(a.x, mask);
        a.y += __shfl_xor(a.y, mask);
        a.z += __shfl_xor(a.z, mask);
        a.w += __shfl_xor(a.w, mask);
    }

    if (lane < F4) {
        uint2 r = reinterpret_cast<const uint2*>(hs + (size_t)node * F)[lane];
        float2 s0 = __half22float2(*reinterpret_cast<__half2*>(&r.x));
        float2 s1 = __half22float2(*reinterpret_cast<__half2*>(&r.y));
        float di = dinv[node];
        int f0 = lane * 4;
        float4 z;
        z.x = di * (a.x + s0.x) + b[f0 + 0];
        z.y = di * (a.y + s0.y) + b[f0 + 1];
        z.z = di * (a.z + s1.x) + b[f0 + 2];
        z.w = di * (a.w + s1.y) + b[f0 + 3];
        if constexpr (MODE == 2) {
            z.x = (z.x - m[f0+0]) * rsqrtf(vv[f0+0] + EPS) * g[f0+0] + be[f0+0];
            z.y = (z.y - m[f0+1]) * rsqrtf(vv[f0+1] + EPS) * g[f0+1] + be[f0+1];
            z.z = (z.z - m[f0+2]) * rsqrtf(vv[f0+2] + EPS) * g[f0+2] + be[f0+2];
            z.w = (z.w - m[f0+3]) * rsqrtf(vv[f0+3] + EPS) * g[f0+3] + be[f0+3];
        }
        z.x = fmaxf(z.x, 0.f); z.y = fmaxf(z.y, 0.f);
        z.z = fmaxf(z.z, 0.f); z.w = fmaxf(z.w, 0.f);
        reinterpret_cast<float4*>(out + (size_t)node * F)[lane] = z;
    }
}

// ---- layer-1 tail: X1 = relu(bn(G[:, :5] @ W1 + b1)) ----------------------
__global__ void k_lin1(const float* __restrict__ G, const float* __restrict__ W1,
                       const float* __restrict__ b1, const float* __restrict__ g1,
                       const float* __restrict__ be1, const float* __restrict__ m1,
                       const float* __restrict__ v1, float* __restrict__ X) {
    int idx = blockIdx.x * blockDim.x + threadIdx.x;
    if (idx >= NN * 64) return;
    int i = idx >> 6, f = idx & 63;
    const float* gr = G + (size_t)i * 8;
    float z = b1[f];
    #pragma unroll
    for (int k = 0; k < 5; ++k) z += gr[k] * W1[k * 64 + f];
    z = (z - m1[f]) * rsqrtf(v1[f] + EPS) * g1[f] + be1[f];
    X[idx] = fmaxf(z, 0.f);
}

extern "C" void kernel_launch(void* const* d_in, const int* in_sizes, int n_in,
                              void* d_out, int out_size, void* d_ws, size_t ws_size,
                              hipStream_t stream) {
    const float* x   = (const float*)d_in[0];
    const int*   src = (const int*)  d_in[1];
    const int*   dst = (const int*)  d_in[2];
    const float* W1  = (const float*)d_in[3];
    const float* b1  = (const float*)d_in[4];
    const float* g1  = (const float*)d_in[5];
    const float* be1 = (const float*)d_in[6];
    const float* m1  = (const float*)d_in[7];
    const float* v1  = (const float*)d_in[8];
    const float* W2  = (const float*)d_in[9];
    const float* b2  = (const float*)d_in[10];
    const float* g2  = (const float*)d_in[11];
    const float* be2 = (const float*)d_in[12];
    const float* m2  = (const float*)d_in[13];
    const float* v2  = (const float*)d_in[14];
    const float* W3  = (const float*)d_in[15];
    const float* b3  = (const float*)d_in[16];
    const float* W4  = (const float*)d_in[17];
    const float* b4  = (const float*)d_in[18];
    float* out = (float*)d_out;

    // workspace layout (4-byte units)
    char* wsb = (char*)d_ws;
    float*    dinv    = (float*)wsb;                    // 100352
    int*      cnt     = (int*)(wsb + 100352ull * 4);    // 100352
    int*      rowp    = (int*)(wsb + 200704ull * 4);    // 100352
    int*      gcur    = (int*)(wsb + 301056ull * 4);    // 512
    int*      binBase = (int*)(wsb + 301568ull * 4);    // 512
    int*      csr     = (int*)(wsb + 302080ull * 4);    // NE
    float*    HS      = (float*)(wsb + (302080ull + NE) * 4);              // NN*64 f32
    __half*   HSh     = (__half*)HS;                                        // f16 view
    float*    X       = (float*)(wsb + (302080ull + NE + 6400000ull) * 4); // NN*64
    unsigned* ebuf    = (unsigned*)X;  // aliases X (NB*CAP2 = 3.6M <= 6.4M)
    float*    G       = (float*)(wsb + (302080ull + NE + 12800000ull) * 4); // NN*8

    const int BLK = 256;
    const int gW  = (NN * 64 + BLK - 1) / BLK;     // wave-per-node
    auto gNF = [&](int f) { return (NN * f + BLK - 1) / BLK; };

    // ---- CSR build (2-pass LDS counting sort) + per-node rowp/cnt/dinv ----
    k_seed   <<<2, 256, 0, stream>>>(gcur);
    k_part1  <<<NBLK1, BLK, 0, stream>>>(src, dst, gcur, ebuf);
    k_binscan<<<1, 512, 0, stream>>>(gcur, binBase);
    k_part2  <<<NB, BLK, 0, stream>>>(ebuf, binBase, csr, rowp, cnt, dinv);

    // ---- Layer 1: gather at F_in=5 (pad 8, f32), then 5->64 GEMM+BN+ReLU ----
    k_stage1<<<gNF(8), BLK, 0, stream>>>(x, dinv, HS);
    k_gather<8, 0><<<gW, BLK, 0, stream>>>(rowp, cnt, csr, HS, dinv, nullptr, G);
    k_lin1<<<gNF(64), BLK, 0, stream>>>(G, W1, b1, g1, be1, m1, v1, X);

    // ---- Layer 2: 64 -> 32 GEMM (f16 hs), gather_h at 32, BN + ReLU ----
    k_linear_scale_h<64, 32><<<gNF(32), BLK, 0, stream>>>(X, W2, dinv, HSh);
    k_gather_h<32, 2><<<gW, BLK, 0, stream>>>(rowp, cnt, csr, HSh, dinv, b2, g2, be2, m2, v2, X);

    // ---- Layer 3: 32 -> 16 GEMM (f16 hs), gather_h at 16, ReLU ----
    k_linear_scale_h<32, 16><<<gNF(16), BLK, 0, stream>>>(X, W3, dinv, HSh);
    k_gather_h<16, 1><<<gW, BLK, 0, stream>>>(rowp, cnt, csr, HSh, dinv, b3,
                                              nullptr, nullptr, nullptr, nullptr, X);

    // ---- Layer 4: 16 -> 3 GEMM (pad 4, f32), gather at 4, logits ----
    k_linear_scale<16, 3, 4><<<gNF(4), BLK, 0, stream>>>(X, W4, dinv, HS);
    k_gather<4, 3><<<gW, BLK, 0, stream>>>(rowp, cnt, csr, HS, dinv, b4, out);
}